// Round 6
// baseline (335.885 us; speedup 1.0000x reference)
//
#include <hip/hip_runtime.h>
#include <hip/hip_bf16.h>
#include <cstdint>
#include <cmath>

#define AS1 __attribute__((address_space(1)))
#define AS3 __attribute__((address_space(3)))

typedef unsigned short u16;
typedef uint32_t u32;
typedef __attribute__((ext_vector_type(8))) __bf16 bf16x8;
typedef __attribute__((ext_vector_type(8))) unsigned short u16x8;
typedef __attribute__((ext_vector_type(4))) float f32x4;

// fp32 -> bf16 round-to-nearest-even
__device__ __forceinline__ u16 f2bf(float f) {
    uint32_t u = __builtin_bit_cast(uint32_t, f);
    return (u16)((u + 0x7fffu + ((u >> 16) & 1u)) >> 16);
}

// order-preserving float -> u32 map (for integer atomicMax); 0 is below all reals
__device__ __forceinline__ u32 f2ord(float f) {
    u32 u = __builtin_bit_cast(u32, f);
    return u ^ (u32)(((int32_t)u >> 31) | 0x80000000);
}
__device__ __forceinline__ float ord2f(u32 v) {
    u32 u = (v & 0x80000000u) ? (v ^ 0x80000000u) : ~v;
    return __builtin_bit_cast(float, u);
}

// ---------------- fused setup kernel ----------------
// blocks [0,2048):    x [32768,128] fp32 -> bf16 xb
// blocks [2048,2112): W1 = [Wd(511); Wa(512); 0] -> bf16 w1b [1024,128]; bias bb[1024]
// blocks [2112,3136): Wl [1024,2046] -> bf16 wlb [1024,2048], second half shifted +1:
//   col c: c<1023 -> Wl[:,c]; c==1023 -> 0; 1024<=c<=2046 -> Wl[:,c-1]; c==2047 -> 0
__global__ void setup_all(const float* __restrict__ x,
                          const float* __restrict__ Wd, const float* __restrict__ bd,
                          const float* __restrict__ Wa, const float* __restrict__ ba,
                          const float* __restrict__ Wl,
                          u16* __restrict__ xb, u16* __restrict__ w1b,
                          float* __restrict__ bb, u16* __restrict__ wlb) {
    const int b = blockIdx.x;
    if (b < 2048) {
        long idx = (long)(b * 256 + threadIdx.x) * 8;
        float4 a = *(const float4*)(x + idx);
        float4 c = *(const float4*)(x + idx + 4);
        u16x8 o;
        o[0]=f2bf(a.x); o[1]=f2bf(a.y); o[2]=f2bf(a.z); o[3]=f2bf(a.w);
        o[4]=f2bf(c.x); o[5]=f2bf(c.y); o[6]=f2bf(c.z); o[7]=f2bf(c.w);
        *(u16x8*)(xb + idx) = o;
    } else if (b < 2112) {
        int t = (b - 2048) * 256 + threadIdx.x;   // 16384 threads
        int row = t >> 4, g = (t & 15) * 8;
        const float* src = nullptr;
        if (row < 511)       src = Wd + row * 128 + g;
        else if (row < 1023) src = Wa + (row - 511) * 128 + g;
        u16x8 o = 0;
        if (src) {
            #pragma unroll
            for (int j = 0; j < 8; ++j) o[j] = f2bf(src[j]);
        }
        *(u16x8*)(w1b + row * 128 + g) = o;
        if ((t & 15) == 0)
            bb[row] = row < 511 ? bd[row] : (row < 1023 ? ba[row - 511] : 0.f);
    } else {
        int t = (b - 2112) * 256 + threadIdx.x;   // 262144 threads
        int row = t >> 8, g = (t & 255) * 8;
        const float* src = Wl + (long)row * 2046;
        u16x8 o;
        #pragma unroll
        for (int j = 0; j < 8; ++j) {
            int c = g + j;
            float v;
            if (c == 1023 || c == 2047) v = 0.f;
            else v = (c < 1023) ? src[c] : src[c - 1];
            o[j] = f2bf(v);
        }
        *(u16x8*)(wlb + (long)row * 2048 + g) = o;
    }
}

// ---------------- MFMA GEMM: C = A(bf16,[M,K]) * B(bf16,[N,K])^T ----------------
// BM=BN=128, BK=32; block=256 threads (4 waves, 2x2), wave tile 64x64 (4x4 of 16x16x32).
// Grid dim3(8,256): linear ID = x + 8y -> XCD = x. mTile = x*32 + (y>>3), nTile = y&7:
// the 8 blocks sharing an A-tile all land on XCD x -> A fetched once per XCD L2
// (round 5: FETCH 145 MB ~= ideal). K-start rotation koff de-synchronizes co-resident
// tile-groups (round 4: lockstep phases -> 2.4e8 LDS conflict cycles; round 5: 2.2e7).
// MODE 0: fused ragged-max epilogue -> pooledPart[nTile][row][16] as ordered u32
// MODE 1: hh epilogue via LDS-staged coalesced u16x8 stores:
//         hh[row, col] = relu(v+b), hh[row, 1024+col] = relu(-(v+b))
template <int MODE>
__global__ __launch_bounds__(256) void gemm_mfma(
        const u16* __restrict__ A, const u16* __restrict__ B, int K,
        u16* __restrict__ outH, const float* __restrict__ bias,
        const int* __restrict__ seg, u32* __restrict__ pp) {
    __shared__ u16 As[128 * 32];
    __shared__ u16 Bs[128 * 32];
    const int tid  = threadIdx.x;
    const int lane = tid & 63, wave = tid >> 6;
    const int wy = wave >> 1, wx = wave & 1;
    const int i16 = lane & 15, q = lane >> 4;

    const int xcd = blockIdx.x;                 // 0..7
    const int y   = blockIdx.y;                 // 0..255
    const int nTile = y & 7;
    const long blockM = (long)(xcd * 32 + (y >> 3)) * 128;
    const int  blockN = nTile * 128;
    const int nch  = K >> 5;                    // K chunks of 32
    const int koff = ((y >> 3) * 2) & (nch - 1);

    f32x4 acc[4][4];
    #pragma unroll
    for (int m = 0; m < 4; ++m)
        #pragma unroll
        for (int n = 0; n < 4; ++n)
            acc[m][n] = f32x4{0.f, 0.f, 0.f, 0.f};

    // staging: chunk c covers 16 rows x 32 cols; lane l -> row c*16 + l/4, col (l%4)*8
    const int cA   = wave * 2;
    const int srow = lane >> 2;
    const int scol = (lane & 3) * 8;
    const u16* a0 = A + (blockM + cA * 16 + srow) * (long)K + scol;
    const u16* a1 = A + (blockM + (cA + 1) * 16 + srow) * (long)K + scol;
    const u16* b0 = B + ((long)blockN + cA * 16 + srow) * K + scol;
    const u16* b1 = B + ((long)blockN + (cA + 1) * 16 + srow) * K + scol;

    for (int it = 0; it < nch; ++it) {
        const int k0 = ((it + koff) & (nch - 1)) << 5;
        __builtin_amdgcn_global_load_lds((const AS1 void*)(a0 + k0), (AS3 void*)&As[cA * 512],       16, 0, 0);
        __builtin_amdgcn_global_load_lds((const AS1 void*)(a1 + k0), (AS3 void*)&As[(cA + 1) * 512], 16, 0, 0);
        __builtin_amdgcn_global_load_lds((const AS1 void*)(b0 + k0), (AS3 void*)&Bs[cA * 512],       16, 0, 0);
        __builtin_amdgcn_global_load_lds((const AS1 void*)(b1 + k0), (AS3 void*)&Bs[(cA + 1) * 512], 16, 0, 0);
        __syncthreads();

        bf16x8 af[4], bfv[4];
        #pragma unroll
        for (int s = 0; s < 4; ++s) {
            af[s]  = *(const bf16x8*)&As[(wy * 64 + s * 16 + i16) * 32 + q * 8];
            bfv[s] = *(const bf16x8*)&Bs[(wx * 64 + s * 16 + i16) * 32 + q * 8];
        }
        #pragma unroll
        for (int sm = 0; sm < 4; ++sm)
            #pragma unroll
            for (int sn = 0; sn < 4; ++sn)
                acc[sm][sn] = __builtin_amdgcn_mfma_f32_16x16x32_bf16(af[sm], bfv[sn], acc[sm][sn], 0, 0, 0);
        __syncthreads();
    }

    // epilogue: D[row = 4q + r][col = i16] per 16x16 subtile (verified C/D layout)
    if constexpr (MODE == 0) {
        __shared__ u32 pmax[128 * 16];
        #pragma unroll
        for (int j = 0; j < 8; ++j) pmax[tid + j * 256] = 0u;   // 0 = below all reals
        __syncthreads();
        int segc[4];
        #pragma unroll
        for (int sn = 0; sn < 4; ++sn) segc[sn] = seg[blockN + wx * 64 + sn * 16 + i16];
        #pragma unroll
        for (int sm = 0; sm < 4; ++sm) {
            #pragma unroll
            for (int sn = 0; sn < 4; ++sn) {
                #pragma unroll
                for (int r = 0; r < 4; ++r) {
                    const int rl = wy * 64 + sm * 16 + 4 * q + r;
                    atomicMax(&pmax[rl * 16 + segc[sn]], f2ord(acc[sm][sn][r]));
                }
            }
        }
        __syncthreads();
        // write partials: pp[nTile][blockM + rl][a] (coalesced, 256 B/wave)
        #pragma unroll
        for (int j = 0; j < 8; ++j) {
            int idx = tid + j * 256;                       // 0..2047
            pp[((long)nTile << 19) + ((blockM + (idx >> 4)) << 4) + (idx & 15)] = pmax[idx];
        }
    } else {
        __shared__ u16 obuf[64 * 136];   // 17.4 KB staging, stride 136 u16 breaks banks
        float bv[4];
        #pragma unroll
        for (int sn = 0; sn < 4; ++sn) bv[sn] = bias[blockN + wx * 64 + sn * 16 + i16];
        // 4 passes: sign (pos/neg) x rowHalf; stage 64x128 bf16, store 256 B row-chunks
        #pragma unroll
        for (int sg = 0; sg < 2; ++sg) {
            #pragma unroll
            for (int rh = 0; rh < 2; ++rh) {
                __syncthreads();
                if (wy == rh) {
                    #pragma unroll
                    for (int sm = 0; sm < 4; ++sm)
                        #pragma unroll
                        for (int sn = 0; sn < 4; ++sn)
                            #pragma unroll
                            for (int r = 0; r < 4; ++r) {
                                const float v = acc[sm][sn][r] + bv[sn];
                                const float pv = sg ? fmaxf(-v, 0.f) : fmaxf(v, 0.f);
                                obuf[(sm * 16 + 4 * q + r) * 136 + wx * 64 + sn * 16 + i16] = f2bf(pv);
                            }
                }
                __syncthreads();
                const int cg = (tid & 15) * 8;
                const int gcol = (sg ? 1024 : 0) + blockN + cg;
                #pragma unroll
                for (int rr = 0; rr < 4; ++rr) {
                    const int row = rr * 16 + (tid >> 4);
                    const long grow = blockM + rh * 64 + row;
                    *(u16x8*)&outH[grow * 2048 + gcol] = *(const u16x8*)&obuf[row * 136 + cg];
                }
            }
        }
    }
}

// ---------------- finalize: max over 8 partials + softmax ----------------
// 256 threads = 16 rows x 16 actions per block; shuffle softmax over width 16
__global__ __launch_bounds__(256) void finalize(const u32* __restrict__ pp,
                                                float* __restrict__ out) {
    const int tid = threadIdx.x;
    const long row = (long)blockIdx.x * 16 + (tid >> 4);
    const int t = tid & 15;
    u32 m = 0;
    #pragma unroll
    for (int p = 0; p < 8; ++p)
        m = max(m, pp[((long)p << 19) + (row << 4) + t]);
    float logit = ord2f(m);
    float rm = logit;
    #pragma unroll
    for (int d = 8; d >= 1; d >>= 1) rm = fmaxf(rm, __shfl_xor(rm, d, 16));
    float e = __expf(logit - rm);
    float s = e;
    #pragma unroll
    for (int d = 8; d >= 1; d >>= 1) s += __shfl_xor(s, d, 16);
    out[(row << 4) + t] = e / s;
}

// ---------------- launch ----------------
extern "C" void kernel_launch(void* const* d_in, const int* in_sizes, int n_in,
                              void* d_out, int out_size, void* d_ws, size_t ws_size,
                              hipStream_t stream) {
    const float* x  = (const float*)d_in[0];
    const float* Wd = (const float*)d_in[1];
    const float* bd = (const float*)d_in[2];
    const float* Wa = (const float*)d_in[3];
    const float* ba = (const float*)d_in[4];
    const float* Wl = (const float*)d_in[5];
    const int*  seg = (const int*)d_in[6];
    float* out = (float*)d_out;

    char* ws = (char*)d_ws;
    u16*   xb  = (u16*)(ws);                       //   8,388,608 B  x bf16 [32768,128]
    u16*   w1b = (u16*)(ws + 8388608);             //     262,144 B  W1 bf16 [1024,128]
    float* bb  = (float*)(ws + 8650752);           //       4,096 B  bias [1024]
    u16*   wlb = (u16*)(ws + 8654848);             //   4,194,304 B  Wl bf16 [1024,2048] (cols shifted)
    u16*   hh  = (u16*)(ws + 12849152);            // 134,217,728 B  hh bf16 [32768,2048]
    u32*   pp  = (u32*)(ws + 147066880);           //  16,777,216 B  pooledPart u32 [8][32768][16]
    // total ws use: 163,844,096 B (~156 MiB)

    setup_all<<<3136, 256, 0, stream>>>(x, Wd, bd, Wa, ba, Wl, xb, w1b, bb, wlb);
    gemm_mfma<1><<<dim3(8, 256), 256, 0, stream>>>(xb, w1b, 128, hh, bb, nullptr, nullptr);
    gemm_mfma<0><<<dim3(8, 256), 256, 0, stream>>>(hh, wlb, 2048, nullptr, nullptr, seg, pp);
    finalize<<<2048, 256, 0, stream>>>(pp, out);
}

// Round 7
// 261.899 us; speedup vs baseline: 1.2825x; 1.2825x over previous
//
#include <hip/hip_runtime.h>
#include <hip/hip_bf16.h>
#include <cstdint>
#include <cmath>

#define AS1 __attribute__((address_space(1)))
#define AS3 __attribute__((address_space(3)))

typedef unsigned short u16;
typedef uint32_t u32;
typedef __attribute__((ext_vector_type(8))) __bf16 bf16x8;
typedef __attribute__((ext_vector_type(8))) unsigned short u16x8;
typedef __attribute__((ext_vector_type(4))) float f32x4;

// fp32 -> bf16 round-to-nearest-even
__device__ __forceinline__ u16 f2bf(float f) {
    uint32_t u = __builtin_bit_cast(uint32_t, f);
    return (u16)((u + 0x7fffu + ((u >> 16) & 1u)) >> 16);
}

// order-preserving float -> u32 map (for integer atomicMax); 0 is below all reals
__device__ __forceinline__ u32 f2ord(float f) {
    u32 u = __builtin_bit_cast(u32, f);
    return u ^ (u32)(((int32_t)u >> 31) | 0x80000000);
}
__device__ __forceinline__ float ord2f(u32 v) {
    u32 u = (v & 0x80000000u) ? (v ^ 0x80000000u) : ~v;
    return __builtin_bit_cast(float, u);
}

// ---------------- fused setup ----------------
// ALGEBRA: relu(h)=(h+|h|)/2, relu(-h)=(|h|-h)/2  =>
//   leaf = |h| @ Ws^T + x @ Wc^T + cl,
//   Ws = (Wl[:, :1023] + Wl[:, 1023:])/2   [1024 x 1024 bf16, col 1023 = 0]
//   Wc = 0.5 * (Wl[:, :1023]-Wl[:, 1023:]) @ W1   [1024 x 128]  (fp32 acc)
//   cl = 0.5 * (Wl[:, :1023]-Wl[:, 1023:]) @ b1   [1024]
// blocks [0,2048):    x [32768,128] fp32 -> bf16 xb
// blocks [2048,2112): w1b = [Wd(511); Wa(512); 0] bf16 [1024,128]; bias bb[1024]
// blocks [2112,2624): wsb [1024,1024]
__global__ void setup_all(const float* __restrict__ x,
                          const float* __restrict__ Wd, const float* __restrict__ bd,
                          const float* __restrict__ Wa, const float* __restrict__ ba,
                          const float* __restrict__ Wl,
                          u16* __restrict__ xb, u16* __restrict__ w1b,
                          float* __restrict__ bb, u16* __restrict__ wsb) {
    const int b = blockIdx.x;
    if (b < 2048) {
        long idx = (long)(b * 256 + threadIdx.x) * 8;
        float4 a = *(const float4*)(x + idx);
        float4 c = *(const float4*)(x + idx + 4);
        u16x8 o;
        o[0]=f2bf(a.x); o[1]=f2bf(a.y); o[2]=f2bf(a.z); o[3]=f2bf(a.w);
        o[4]=f2bf(c.x); o[5]=f2bf(c.y); o[6]=f2bf(c.z); o[7]=f2bf(c.w);
        *(u16x8*)(xb + idx) = o;
    } else if (b < 2112) {
        int t = (b - 2048) * 256 + threadIdx.x;   // 16384 threads
        int row = t >> 4, g = (t & 15) * 8;
        const float* src = nullptr;
        if (row < 511)       src = Wd + row * 128 + g;
        else if (row < 1023) src = Wa + (row - 511) * 128 + g;
        u16x8 o = 0;
        if (src) {
            #pragma unroll
            for (int j = 0; j < 8; ++j) o[j] = f2bf(src[j]);
        }
        *(u16x8*)(w1b + row * 128 + g) = o;
        if ((t & 15) == 0)
            bb[row] = row < 511 ? bd[row] : (row < 1023 ? ba[row - 511] : 0.f);
    } else {
        int t = (b - 2112) * 256 + threadIdx.x;   // 131072 threads
        int row = t >> 7, g = (t & 127) * 8;
        const float* src = Wl + (long)row * 2046;
        u16x8 o;
        #pragma unroll
        for (int j = 0; j < 8; ++j) {
            int c = g + j;
            o[j] = (c < 1023) ? f2bf(0.5f * (src[c] + src[1023 + c])) : (u16)0;
        }
        *(u16x8*)(wsb + (long)row * 1024 + g) = o;
    }
}

// Wc [1024,128] bf16 + cl [1024] fp32. Block = 2 leaf rows; thread (lo=tid>>7, i=tid&127).
__global__ __launch_bounds__(256) void build_wc(const float* __restrict__ Wl,
        const float* __restrict__ Wd, const float* __restrict__ bd,
        const float* __restrict__ Wa, const float* __restrict__ ba,
        u16* __restrict__ wcb, float* __restrict__ cl) {
    __shared__ float dl[2][1024];
    __shared__ float b1s[1024];
    __shared__ float cred[256];
    const int tid = threadIdx.x;
    const int l0 = blockIdx.x * 2;
    const float* r0 = Wl + (long)l0 * 2046;
    const float* r1 = Wl + (long)(l0 + 1) * 2046;
    for (int j = tid; j < 1023; j += 256) {
        b1s[j]   = j < 511 ? bd[j] : ba[j - 511];
        dl[0][j] = r0[j] - r0[1023 + j];
        dl[1][j] = r1[j] - r1[1023 + j];
    }
    __syncthreads();
    const int lo = tid >> 7, i = tid & 127;
    float s = 0.f;
    #pragma unroll 8
    for (int j = 0; j < 511; ++j)  s += dl[lo][j] * Wd[j * 128 + i];
    #pragma unroll 8
    for (int j = 511; j < 1023; ++j) s += dl[lo][j] * Wa[(j - 511) * 128 + i];
    wcb[(l0 + lo) * 128 + i] = f2bf(0.5f * s);
    float c = 0.f;
    for (int j = i; j < 1023; j += 128) c += dl[lo][j] * b1s[j];
    cred[tid] = c;
    __syncthreads();
    if (tid < 2) {
        float cs = 0.f;
        #pragma unroll
        for (int k = 0; k < 128; ++k) cs += cred[tid * 128 + k];
        cl[l0 + tid] = 0.5f * cs;
    }
}

// ---------------- GEMM1: habs = |xb @ w1b^T + bb|, bf16 [32768,1024] ----------------
// m97 structure, BM=BN=128, BK=32, K=128 (4 iters). XCD swizzle + koff rotation
// (round 4/5 lesson: lockstep phases -> LDS conflict storm). Scatter epilogue (L2 absorbs).
__global__ __launch_bounds__(256) void gemm_h(const u16* __restrict__ A,
        const u16* __restrict__ B, const float* __restrict__ bias,
        u16* __restrict__ habs) {
    __shared__ u16 As[128 * 32];
    __shared__ u16 Bs[128 * 32];
    const int tid  = threadIdx.x;
    const int lane = tid & 63, wave = tid >> 6;
    const int wy = wave >> 1, wx = wave & 1;
    const int i16 = lane & 15, q = lane >> 4;
    const int xcd = blockIdx.x, y = blockIdx.y;
    const long blockM = (long)(xcd * 32 + (y >> 3)) * 128;
    const int  blockN = (y & 7) * 128;
    const int  koff = ((y >> 3) * 2) & 3;

    f32x4 acc[4][4];
    #pragma unroll
    for (int m = 0; m < 4; ++m)
        #pragma unroll
        for (int n = 0; n < 4; ++n) acc[m][n] = f32x4{0.f,0.f,0.f,0.f};

    const int cA = wave * 2, srow = lane >> 2, scol = (lane & 3) * 8;
    const u16* a0 = A + (blockM + cA * 16 + srow) * 128 + scol;
    const u16* a1 = A + (blockM + (cA + 1) * 16 + srow) * 128 + scol;
    const u16* b0 = B + ((long)blockN + cA * 16 + srow) * 128 + scol;
    const u16* b1 = B + ((long)blockN + (cA + 1) * 16 + srow) * 128 + scol;

    for (int it = 0; it < 4; ++it) {
        const int k0 = ((it + koff) & 3) << 5;
        __builtin_amdgcn_global_load_lds((const AS1 void*)(a0 + k0), (AS3 void*)&As[cA * 512],       16, 0, 0);
        __builtin_amdgcn_global_load_lds((const AS1 void*)(a1 + k0), (AS3 void*)&As[(cA + 1) * 512], 16, 0, 0);
        __builtin_amdgcn_global_load_lds((const AS1 void*)(b0 + k0), (AS3 void*)&Bs[cA * 512],       16, 0, 0);
        __builtin_amdgcn_global_load_lds((const AS1 void*)(b1 + k0), (AS3 void*)&Bs[(cA + 1) * 512], 16, 0, 0);
        __syncthreads();
        bf16x8 af[4], bfv[4];
        #pragma unroll
        for (int s = 0; s < 4; ++s) {
            af[s]  = *(const bf16x8*)&As[(wy * 64 + s * 16 + i16) * 32 + q * 8];
            bfv[s] = *(const bf16x8*)&Bs[(wx * 64 + s * 16 + i16) * 32 + q * 8];
        }
        #pragma unroll
        for (int sm = 0; sm < 4; ++sm)
            #pragma unroll
            for (int sn = 0; sn < 4; ++sn)
                acc[sm][sn] = __builtin_amdgcn_mfma_f32_16x16x32_bf16(af[sm], bfv[sn], acc[sm][sn], 0, 0, 0);
        __syncthreads();
    }
    float bv[4];
    #pragma unroll
    for (int sn = 0; sn < 4; ++sn) bv[sn] = bias[blockN + wx * 64 + sn * 16 + i16];
    #pragma unroll
    for (int sm = 0; sm < 4; ++sm)
        #pragma unroll
        for (int sn = 0; sn < 4; ++sn) {
            const int col = blockN + wx * 64 + sn * 16 + i16;
            #pragma unroll
            for (int r = 0; r < 4; ++r) {
                const long row = blockM + wy * 64 + sm * 16 + 4 * q + r;
                habs[row * 1024 + col] = f2bf(fabsf(acc[sm][sn][r] + bv[sn]));
            }
        }
}

// ---------------- GEMM2': leaf = habs@Ws^T + xb@Wc^T + cl, fused ragged-max ----------
// Two-phase K-loop: 32 chunks over habs (K=1024, rotated) + 4 chunks over xb (K=128).
// Epilogue: +cl[l], LDS atomicMax into pmax[128][16], partials -> pp[nTile][row][16].
__global__ __launch_bounds__(256) void gemm_leaf(const u16* __restrict__ habs,
        const u16* __restrict__ xb, const u16* __restrict__ wsb,
        const u16* __restrict__ wcb, const float* __restrict__ cl,
        const int* __restrict__ seg, u32* __restrict__ pp) {
    __shared__ u16 As[128 * 32];
    __shared__ u16 Bs[128 * 32];
    __shared__ u32 pmax[128 * 16];
    const int tid  = threadIdx.x;
    const int lane = tid & 63, wave = tid >> 6;
    const int wy = wave >> 1, wx = wave & 1;
    const int i16 = lane & 15, q = lane >> 4;
    const int xcd = blockIdx.x, y = blockIdx.y;
    const int nTile = y & 7;
    const long blockM = (long)(xcd * 32 + (y >> 3)) * 128;
    const int  blockN = nTile * 128;
    const int  koff = ((y >> 3) * 2) & 31;

    #pragma unroll
    for (int j = 0; j < 8; ++j) pmax[tid + j * 256] = 0u;   // below all reals

    f32x4 acc[4][4];
    #pragma unroll
    for (int m = 0; m < 4; ++m)
        #pragma unroll
        for (int n = 0; n < 4; ++n) acc[m][n] = f32x4{0.f,0.f,0.f,0.f};

    const int cA = wave * 2, srow = lane >> 2, scol = (lane & 3) * 8;
    // phase 1: habs (stride 1024) x wsb (stride 1024)
    {
        const u16* a0 = habs + (blockM + cA * 16 + srow) * 1024 + scol;
        const u16* a1 = habs + (blockM + (cA + 1) * 16 + srow) * 1024 + scol;
        const u16* b0 = wsb + ((long)blockN + cA * 16 + srow) * 1024 + scol;
        const u16* b1 = wsb + ((long)blockN + (cA + 1) * 16 + srow) * 1024 + scol;
        for (int it = 0; it < 32; ++it) {
            const int k0 = ((it + koff) & 31) << 5;
            __builtin_amdgcn_global_load_lds((const AS1 void*)(a0 + k0), (AS3 void*)&As[cA * 512],       16, 0, 0);
            __builtin_amdgcn_global_load_lds((const AS1 void*)(a1 + k0), (AS3 void*)&As[(cA + 1) * 512], 16, 0, 0);
            __builtin_amdgcn_global_load_lds((const AS1 void*)(b0 + k0), (AS3 void*)&Bs[cA * 512],       16, 0, 0);
            __builtin_amdgcn_global_load_lds((const AS1 void*)(b1 + k0), (AS3 void*)&Bs[(cA + 1) * 512], 16, 0, 0);
            __syncthreads();
            bf16x8 af[4], bfv[4];
            #pragma unroll
            for (int s = 0; s < 4; ++s) {
                af[s]  = *(const bf16x8*)&As[(wy * 64 + s * 16 + i16) * 32 + q * 8];
                bfv[s] = *(const bf16x8*)&Bs[(wx * 64 + s * 16 + i16) * 32 + q * 8];
            }
            #pragma unroll
            for (int sm = 0; sm < 4; ++sm)
                #pragma unroll
                for (int sn = 0; sn < 4; ++sn)
                    acc[sm][sn] = __builtin_amdgcn_mfma_f32_16x16x32_bf16(af[sm], bfv[sn], acc[sm][sn], 0, 0, 0);
            __syncthreads();
        }
    }
    // phase 2: xb (stride 128) x wcb (stride 128)
    {
        const u16* a0 = xb + (blockM + cA * 16 + srow) * 128 + scol;
        const u16* a1 = xb + (blockM + (cA + 1) * 16 + srow) * 128 + scol;
        const u16* b0 = wcb + ((long)blockN + cA * 16 + srow) * 128 + scol;
        const u16* b1 = wcb + ((long)blockN + (cA + 1) * 16 + srow) * 128 + scol;
        for (int it = 0; it < 4; ++it) {
            const int k0 = it << 5;
            __builtin_amdgcn_global_load_lds((const AS1 void*)(a0 + k0), (AS3 void*)&As[cA * 512],       16, 0, 0);
            __builtin_amdgcn_global_load_lds((const AS1 void*)(a1 + k0), (AS3 void*)&As[(cA + 1) * 512], 16, 0, 0);
            __builtin_amdgcn_global_load_lds((const AS1 void*)(b0 + k0), (AS3 void*)&Bs[cA * 512],       16, 0, 0);
            __builtin_amdgcn_global_load_lds((const AS1 void*)(b1 + k0), (AS3 void*)&Bs[(cA + 1) * 512], 16, 0, 0);
            __syncthreads();
            bf16x8 af[4], bfv[4];
            #pragma unroll
            for (int s = 0; s < 4; ++s) {
                af[s]  = *(const bf16x8*)&As[(wy * 64 + s * 16 + i16) * 32 + q * 8];
                bfv[s] = *(const bf16x8*)&Bs[(wx * 64 + s * 16 + i16) * 32 + q * 8];
            }
            #pragma unroll
            for (int sm = 0; sm < 4; ++sm)
                #pragma unroll
                for (int sn = 0; sn < 4; ++sn)
                    acc[sm][sn] = __builtin_amdgcn_mfma_f32_16x16x32_bf16(af[sm], bfv[sn], acc[sm][sn], 0, 0, 0);
            __syncthreads();
        }
    }

    // epilogue: D[row = 4q + r][col = i16]; leaf = acc + cl[col]
    int segc[4]; float clv[4];
    #pragma unroll
    for (int sn = 0; sn < 4; ++sn) {
        const int col = blockN + wx * 64 + sn * 16 + i16;
        segc[sn] = seg[col];
        clv[sn]  = cl[col];
    }
    #pragma unroll
    for (int sm = 0; sm < 4; ++sm)
        #pragma unroll
        for (int sn = 0; sn < 4; ++sn)
            #pragma unroll
            for (int r = 0; r < 4; ++r) {
                const int rl = wy * 64 + sm * 16 + 4 * q + r;
                atomicMax(&pmax[rl * 16 + segc[sn]], f2ord(acc[sm][sn][r] + clv[sn]));
            }
    __syncthreads();
    #pragma unroll
    for (int j = 0; j < 8; ++j) {
        int idx = tid + j * 256;                       // 0..2047
        pp[((long)nTile << 19) + ((blockM + (idx >> 4)) << 4) + (idx & 15)] = pmax[idx];
    }
}

// ---------------- finalize: max over 8 partials + softmax ----------------
__global__ __launch_bounds__(256) void finalize(const u32* __restrict__ pp,
                                                float* __restrict__ out) {
    const int tid = threadIdx.x;
    const long row = (long)blockIdx.x * 16 + (tid >> 4);
    const int t = tid & 15;
    u32 m = 0;
    #pragma unroll
    for (int p = 0; p < 8; ++p)
        m = max(m, pp[((long)p << 19) + (row << 4) + t]);
    float logit = ord2f(m);
    float rm = logit;
    #pragma unroll
    for (int d = 8; d >= 1; d >>= 1) rm = fmaxf(rm, __shfl_xor(rm, d, 16));
    float e = __expf(logit - rm);
    float s = e;
    #pragma unroll
    for (int d = 8; d >= 1; d >>= 1) s += __shfl_xor(s, d, 16);
    out[(row << 4) + t] = e / s;
}

// ---------------- launch ----------------
extern "C" void kernel_launch(void* const* d_in, const int* in_sizes, int n_in,
                              void* d_out, int out_size, void* d_ws, size_t ws_size,
                              hipStream_t stream) {
    const float* x  = (const float*)d_in[0];
    const float* Wd = (const float*)d_in[1];
    const float* bd = (const float*)d_in[2];
    const float* Wa = (const float*)d_in[3];
    const float* ba = (const float*)d_in[4];
    const float* Wl = (const float*)d_in[5];
    const int*  seg = (const int*)d_in[6];
    float* out = (float*)d_out;

    char* ws = (char*)d_ws;
    u16*   xb   = (u16*)(ws);                      //   8,388,608 B  x bf16 [32768,128]
    u16*   w1b  = (u16*)(ws + 8388608);            //     262,144 B  W1 bf16 [1024,128]
    float* bb   = (float*)(ws + 8650752);          //       4,096 B  bias [1024]
    u16*   wsb  = (u16*)(ws + 8654848);            //   2,097,152 B  Ws bf16 [1024,1024]
    u16*   wcb  = (u16*)(ws + 10752000);           //     262,144 B  Wc bf16 [1024,128]
    float* clp  = (float*)(ws + 11014144);         //       4,096 B  cl fp32 [1024]
    u16*   habs = (u16*)(ws + 11018240);           //  67,108,864 B  |h| bf16 [32768,1024]
    u32*   pp   = (u32*)(ws + 78127104);           //  16,777,216 B  pooledPart u32 [8][32768][16]
    // total ws use: 94,904,320 B (~90.5 MiB)

    setup_all<<<2624, 256, 0, stream>>>(x, Wd, bd, Wa, ba, Wl, xb, w1b, bb, wsb);
    build_wc<<<512, 256, 0, stream>>>(Wl, Wd, bd, Wa, ba, wcb, clp);
    gemm_h   <<<dim3(8, 256), 256, 0, stream>>>(xb, w1b, bb, habs);
    gemm_leaf<<<dim3(8, 256), 256, 0, stream>>>(habs, xb, wsb, wcb, clp, seg, pp);
    finalize <<<2048, 256, 0, stream>>>(pp, out);
}

// Round 8
// 243.267 us; speedup vs baseline: 1.3807x; 1.0766x over previous
//
#include <hip/hip_runtime.h>
#include <hip/hip_bf16.h>
#include <cstdint>
#include <cmath>

#define AS1 __attribute__((address_space(1)))
#define AS3 __attribute__((address_space(3)))

typedef unsigned short u16;
typedef uint32_t u32;
typedef __attribute__((ext_vector_type(8))) __bf16 bf16x8;
typedef __attribute__((ext_vector_type(8))) unsigned short u16x8;
typedef __attribute__((ext_vector_type(4))) float f32x4;

// fp32 -> bf16 round-to-nearest-even
__device__ __forceinline__ u16 f2bf(float f) {
    uint32_t u = __builtin_bit_cast(uint32_t, f);
    return (u16)((u + 0x7fffu + ((u >> 16) & 1u)) >> 16);
}

// order-preserving float -> u32 map (for integer atomicMax); 0 is below all reals
__device__ __forceinline__ u32 f2ord(float f) {
    u32 u = __builtin_bit_cast(u32, f);
    return u ^ (u32)(((int32_t)u >> 31) | 0x80000000);
}
__device__ __forceinline__ float ord2f(u32 v) {
    u32 u = (v & 0x80000000u) ? (v ^ 0x80000000u) : ~v;
    return __builtin_bit_cast(float, u);
}

// ---------------- fused setup ----------------
// ALGEBRA: relu(h)=(h+|h|)/2, relu(-h)=(|h|-h)/2  =>
//   leaf = |h| @ Ws^T + x @ Wc^T + cl,
//   Ws = (Wl[:, :1023] + Wl[:, 1023:])/2      [1024 x 1024 bf16, col 1023 = 0]
//   Dl = Wl[:, :1023] - Wl[:, 1023:]          [1024 x 1024 bf16, col 1023 = 0]
//   Wc = 0.5 * Dl @ W1  (via MFMA gemm_wc)    [1024 x 128 bf16]
//   cl = 0.5 * Dl @ b1  (fp32, fused here)    [1024]
// blocks [0,2048):    x [32768,128] fp32 -> bf16 xb
// blocks [2048,2112): w1b [1024,128] + bias bb[1024] + w1t = W1^T [128,1024]
// blocks [2112,2624): wsb [1024,1024]
// blocks [2624,3136): dlb [1024,1024] + cl[1024]
__global__ void setup_all(const float* __restrict__ x,
                          const float* __restrict__ Wd, const float* __restrict__ bd,
                          const float* __restrict__ Wa, const float* __restrict__ ba,
                          const float* __restrict__ Wl,
                          u16* __restrict__ xb, u16* __restrict__ w1b,
                          float* __restrict__ bb, u16* __restrict__ w1t,
                          u16* __restrict__ wsb, u16* __restrict__ dlb,
                          float* __restrict__ cl) {
    __shared__ float cred[256];
    const int b = blockIdx.x;
    const int tid = threadIdx.x;
    if (b < 2048) {
        long idx = (long)(b * 256 + tid) * 8;
        float4 a = *(const float4*)(x + idx);
        float4 c = *(const float4*)(x + idx + 4);
        u16x8 o;
        o[0]=f2bf(a.x); o[1]=f2bf(a.y); o[2]=f2bf(a.z); o[3]=f2bf(a.w);
        o[4]=f2bf(c.x); o[5]=f2bf(c.y); o[6]=f2bf(c.z); o[7]=f2bf(c.w);
        *(u16x8*)(xb + idx) = o;
    } else if (b < 2112) {
        int t = (b - 2048) * 256 + tid;   // 16384 threads
        int row = t >> 4, g = (t & 15) * 8;
        const float* src = nullptr;
        if (row < 511)       src = Wd + row * 128 + g;
        else if (row < 1023) src = Wa + (row - 511) * 128 + g;
        u16x8 o = 0;
        if (src) {
            #pragma unroll
            for (int j = 0; j < 8; ++j) o[j] = f2bf(src[j]);
        }
        *(u16x8*)(w1b + row * 128 + g) = o;
        #pragma unroll
        for (int j = 0; j < 8; ++j) w1t[(g + j) * 1024 + row] = o[j];
        if ((t & 15) == 0)
            bb[row] = row < 511 ? bd[row] : (row < 1023 ? ba[row - 511] : 0.f);
    } else if (b < 2624) {
        int t = (b - 2112) * 256 + tid;   // 131072 threads
        int row = t >> 7, g = (t & 127) * 8;
        const float* src = Wl + (long)row * 2046;
        u16x8 o;
        #pragma unroll
        for (int j = 0; j < 8; ++j) {
            int c = g + j;
            o[j] = (c < 1023) ? f2bf(0.5f * (src[c] + src[1023 + c])) : (u16)0;
        }
        *(u16x8*)(wsb + (long)row * 1024 + g) = o;
    } else {
        const int l0 = (b - 2624) * 2;
        const int lo = tid >> 7, g = (tid & 127) * 8;
        const float* src = Wl + (long)(l0 + lo) * 2046;
        u16x8 o;
        float part = 0.f;
        #pragma unroll
        for (int j = 0; j < 8; ++j) {
            int c = g + j;
            float v = (c < 1023) ? (src[c] - src[1023 + c]) : 0.f;
            o[j] = f2bf(v);
            float b1 = c < 511 ? bd[c] : (c < 1023 ? ba[c - 511] : 0.f);
            part += v * b1;
        }
        *(u16x8*)(dlb + (long)(l0 + lo) * 1024 + g) = o;
        cred[tid] = part;
        __syncthreads();
        if (tid < 2) {
            float s = 0.f;
            #pragma unroll
            for (int k = 0; k < 128; ++k) s += cred[tid * 128 + k];
            cl[l0 + tid] = 0.5f * s;
        }
    }
}

// ---------------- gemm_wc: Wc = 0.5 * dlb @ w1t^T  [1024 x 128] ----------------
// 8 blocks (M-tiles), N=128 (1 tile), K=1024 (32 chunks). Same m97 inner structure.
__global__ __launch_bounds__(256) void gemm_wc(const u16* __restrict__ A,
        const u16* __restrict__ B, u16* __restrict__ wcb) {
    __shared__ u16 As[128 * 32];
    __shared__ u16 Bs[128 * 32];
    const int tid  = threadIdx.x;
    const int lane = tid & 63, wave = tid >> 6;
    const int wy = wave >> 1, wx = wave & 1;
    const int i16 = lane & 15, q = lane >> 4;
    const long blockM = (long)blockIdx.x * 128;
    const int koff = (blockIdx.x * 4) & 31;

    f32x4 acc[4][4];
    #pragma unroll
    for (int m = 0; m < 4; ++m)
        #pragma unroll
        for (int n = 0; n < 4; ++n) acc[m][n] = f32x4{0.f,0.f,0.f,0.f};

    const int cA = wave * 2, srow = lane >> 2, scol = (lane & 3) * 8;
    const u16* a0 = A + (blockM + cA * 16 + srow) * 1024 + scol;
    const u16* a1 = A + (blockM + (cA + 1) * 16 + srow) * 1024 + scol;
    const u16* b0 = B + (long)(cA * 16 + srow) * 1024 + scol;
    const u16* b1 = B + (long)((cA + 1) * 16 + srow) * 1024 + scol;

    for (int it = 0; it < 32; ++it) {
        const int k0 = ((it + koff) & 31) << 5;
        __builtin_amdgcn_global_load_lds((const AS1 void*)(a0 + k0), (AS3 void*)&As[cA * 512],       16, 0, 0);
        __builtin_amdgcn_global_load_lds((const AS1 void*)(a1 + k0), (AS3 void*)&As[(cA + 1) * 512], 16, 0, 0);
        __builtin_amdgcn_global_load_lds((const AS1 void*)(b0 + k0), (AS3 void*)&Bs[cA * 512],       16, 0, 0);
        __builtin_amdgcn_global_load_lds((const AS1 void*)(b1 + k0), (AS3 void*)&Bs[(cA + 1) * 512], 16, 0, 0);
        __syncthreads();
        bf16x8 af[4], bfv[4];
        #pragma unroll
        for (int s = 0; s < 4; ++s) {
            af[s]  = *(const bf16x8*)&As[(wy * 64 + s * 16 + i16) * 32 + q * 8];
            bfv[s] = *(const bf16x8*)&Bs[(wx * 64 + s * 16 + i16) * 32 + q * 8];
        }
        #pragma unroll
        for (int sm = 0; sm < 4; ++sm)
            #pragma unroll
            for (int sn = 0; sn < 4; ++sn)
                acc[sm][sn] = __builtin_amdgcn_mfma_f32_16x16x32_bf16(af[sm], bfv[sn], acc[sm][sn], 0, 0, 0);
        __syncthreads();
    }
    #pragma unroll
    for (int sm = 0; sm < 4; ++sm)
        #pragma unroll
        for (int sn = 0; sn < 4; ++sn) {
            const int col = wx * 64 + sn * 16 + i16;     // 0..127
            #pragma unroll
            for (int r = 0; r < 4; ++r) {
                const long row = blockM + wy * 64 + sm * 16 + 4 * q + r;
                wcb[row * 128 + col] = f2bf(0.5f * acc[sm][sn][r]);
            }
        }
}

// ---------------- GEMM1: habs = |xb @ w1b^T + bb|, bf16 [32768,1024] ----------------
// K=128 (4 iters). XCD swizzle + koff rotation. Single-pass LDS-staged epilogue:
// round-7 scatter version issued 64x 2B stores/thread (store-issue-bound, ~100 us);
// staged: 8x 16B coalesced stores/thread.
__global__ __launch_bounds__(256) void gemm_h(const u16* __restrict__ A,
        const u16* __restrict__ B, const float* __restrict__ bias,
        u16* __restrict__ habs) {
    __shared__ u16 As[128 * 32];
    __shared__ u16 Bs[128 * 32];
    __shared__ u16 obuf[128 * 136];   // 34.8 KB; total 51 KB -> 3 blocks/CU
    const int tid  = threadIdx.x;
    const int lane = tid & 63, wave = tid >> 6;
    const int wy = wave >> 1, wx = wave & 1;
    const int i16 = lane & 15, q = lane >> 4;
    const int xcd = blockIdx.x, y = blockIdx.y;
    const long blockM = (long)(xcd * 32 + (y >> 3)) * 128;
    const int  blockN = (y & 7) * 128;
    const int  koff = ((y >> 3) * 2) & 3;

    f32x4 acc[4][4];
    #pragma unroll
    for (int m = 0; m < 4; ++m)
        #pragma unroll
        for (int n = 0; n < 4; ++n) acc[m][n] = f32x4{0.f,0.f,0.f,0.f};

    const int cA = wave * 2, srow = lane >> 2, scol = (lane & 3) * 8;
    const u16* a0 = A + (blockM + cA * 16 + srow) * 128 + scol;
    const u16* a1 = A + (blockM + (cA + 1) * 16 + srow) * 128 + scol;
    const u16* b0 = B + ((long)blockN + cA * 16 + srow) * 128 + scol;
    const u16* b1 = B + ((long)blockN + (cA + 1) * 16 + srow) * 128 + scol;

    for (int it = 0; it < 4; ++it) {
        const int k0 = ((it + koff) & 3) << 5;
        __builtin_amdgcn_global_load_lds((const AS1 void*)(a0 + k0), (AS3 void*)&As[cA * 512],       16, 0, 0);
        __builtin_amdgcn_global_load_lds((const AS1 void*)(a1 + k0), (AS3 void*)&As[(cA + 1) * 512], 16, 0, 0);
        __builtin_amdgcn_global_load_lds((const AS1 void*)(b0 + k0), (AS3 void*)&Bs[cA * 512],       16, 0, 0);
        __builtin_amdgcn_global_load_lds((const AS1 void*)(b1 + k0), (AS3 void*)&Bs[(cA + 1) * 512], 16, 0, 0);
        __syncthreads();
        bf16x8 af[4], bfv[4];
        #pragma unroll
        for (int s = 0; s < 4; ++s) {
            af[s]  = *(const bf16x8*)&As[(wy * 64 + s * 16 + i16) * 32 + q * 8];
            bfv[s] = *(const bf16x8*)&Bs[(wx * 64 + s * 16 + i16) * 32 + q * 8];
        }
        #pragma unroll
        for (int sm = 0; sm < 4; ++sm)
            #pragma unroll
            for (int sn = 0; sn < 4; ++sn)
                acc[sm][sn] = __builtin_amdgcn_mfma_f32_16x16x32_bf16(af[sm], bfv[sn], acc[sm][sn], 0, 0, 0);
        __syncthreads();
    }
    // stage |acc + b| into obuf (C-layout scatter, LDS absorbs), then coalesced store
    float bv[4];
    #pragma unroll
    for (int sn = 0; sn < 4; ++sn) bv[sn] = bias[blockN + wx * 64 + sn * 16 + i16];
    #pragma unroll
    for (int sm = 0; sm < 4; ++sm)
        #pragma unroll
        for (int sn = 0; sn < 4; ++sn)
            #pragma unroll
            for (int r = 0; r < 4; ++r)
                obuf[(wy * 64 + sm * 16 + 4 * q + r) * 136 + wx * 64 + sn * 16 + i16] =
                    f2bf(fabsf(acc[sm][sn][r] + bv[sn]));
    __syncthreads();
    const int cg = (tid & 15) * 8;
    #pragma unroll
    for (int it = 0; it < 8; ++it) {
        const int row = it * 16 + (tid >> 4);
        *(u16x8*)&habs[(blockM + row) * 1024 + blockN + cg] =
            *(const u16x8*)&obuf[row * 136 + cg];
    }
}

// ---------------- GEMM2': leaf = habs@Ws^T + xb@Wc^T + cl, fused ragged-max ----------
// Two-phase K-loop: 32 chunks over habs (K=1024, rotated) + 4 chunks over xb (K=128).
// Epilogue: +cl[l], LDS atomicMax into pmax[128][16], partials -> pp[nTile][row][16].
__global__ __launch_bounds__(256) void gemm_leaf(const u16* __restrict__ habs,
        const u16* __restrict__ xb, const u16* __restrict__ wsb,
        const u16* __restrict__ wcb, const float* __restrict__ cl,
        const int* __restrict__ seg, u32* __restrict__ pp) {
    __shared__ u16 As[128 * 32];
    __shared__ u16 Bs[128 * 32];
    __shared__ u32 pmax[128 * 16];
    const int tid  = threadIdx.x;
    const int lane = tid & 63, wave = tid >> 6;
    const int wy = wave >> 1, wx = wave & 1;
    const int i16 = lane & 15, q = lane >> 4;
    const int xcd = blockIdx.x, y = blockIdx.y;
    const int nTile = y & 7;
    const long blockM = (long)(xcd * 32 + (y >> 3)) * 128;
    const int  blockN = nTile * 128;
    const int  koff = ((y >> 3) * 2) & 31;

    #pragma unroll
    for (int j = 0; j < 8; ++j) pmax[tid + j * 256] = 0u;   // below all reals

    f32x4 acc[4][4];
    #pragma unroll
    for (int m = 0; m < 4; ++m)
        #pragma unroll
        for (int n = 0; n < 4; ++n) acc[m][n] = f32x4{0.f,0.f,0.f,0.f};

    const int cA = wave * 2, srow = lane >> 2, scol = (lane & 3) * 8;
    // phase 1: habs (stride 1024) x wsb (stride 1024)
    {
        const u16* a0 = habs + (blockM + cA * 16 + srow) * 1024 + scol;
        const u16* a1 = habs + (blockM + (cA + 1) * 16 + srow) * 1024 + scol;
        const u16* b0 = wsb + ((long)blockN + cA * 16 + srow) * 1024 + scol;
        const u16* b1 = wsb + ((long)blockN + (cA + 1) * 16 + srow) * 1024 + scol;
        for (int it = 0; it < 32; ++it) {
            const int k0 = ((it + koff) & 31) << 5;
            __builtin_amdgcn_global_load_lds((const AS1 void*)(a0 + k0), (AS3 void*)&As[cA * 512],       16, 0, 0);
            __builtin_amdgcn_global_load_lds((const AS1 void*)(a1 + k0), (AS3 void*)&As[(cA + 1) * 512], 16, 0, 0);
            __builtin_amdgcn_global_load_lds((const AS1 void*)(b0 + k0), (AS3 void*)&Bs[cA * 512],       16, 0, 0);
            __builtin_amdgcn_global_load_lds((const AS1 void*)(b1 + k0), (AS3 void*)&Bs[(cA + 1) * 512], 16, 0, 0);
            __syncthreads();
            bf16x8 af[4], bfv[4];
            #pragma unroll
            for (int s = 0; s < 4; ++s) {
                af[s]  = *(const bf16x8*)&As[(wy * 64 + s * 16 + i16) * 32 + q * 8];
                bfv[s] = *(const bf16x8*)&Bs[(wx * 64 + s * 16 + i16) * 32 + q * 8];
            }
            #pragma unroll
            for (int sm = 0; sm < 4; ++sm)
                #pragma unroll
                for (int sn = 0; sn < 4; ++sn)
                    acc[sm][sn] = __builtin_amdgcn_mfma_f32_16x16x32_bf16(af[sm], bfv[sn], acc[sm][sn], 0, 0, 0);
            __syncthreads();
        }
    }
    // phase 2: xb (stride 128) x wcb (stride 128)
    {
        const u16* a0 = xb + (blockM + cA * 16 + srow) * 128 + scol;
        const u16* a1 = xb + (blockM + (cA + 1) * 16 + srow) * 128 + scol;
        const u16* b0 = wcb + ((long)blockN + cA * 16 + srow) * 128 + scol;
        const u16* b1 = wcb + ((long)blockN + (cA + 1) * 16 + srow) * 128 + scol;
        for (int it = 0; it < 4; ++it) {
            const int k0 = it << 5;
            __builtin_amdgcn_global_load_lds((const AS1 void*)(a0 + k0), (AS3 void*)&As[cA * 512],       16, 0, 0);
            __builtin_amdgcn_global_load_lds((const AS1 void*)(a1 + k0), (AS3 void*)&As[(cA + 1) * 512], 16, 0, 0);
            __builtin_amdgcn_global_load_lds((const AS1 void*)(b0 + k0), (AS3 void*)&Bs[cA * 512],       16, 0, 0);
            __builtin_amdgcn_global_load_lds((const AS1 void*)(b1 + k0), (AS3 void*)&Bs[(cA + 1) * 512], 16, 0, 0);
            __syncthreads();
            bf16x8 af[4], bfv[4];
            #pragma unroll
            for (int s = 0; s < 4; ++s) {
                af[s]  = *(const bf16x8*)&As[(wy * 64 + s * 16 + i16) * 32 + q * 8];
                bfv[s] = *(const bf16x8*)&Bs[(wx * 64 + s * 16 + i16) * 32 + q * 8];
            }
            #pragma unroll
            for (int sm = 0; sm < 4; ++sm)
                #pragma unroll
                for (int sn = 0; sn < 4; ++sn)
                    acc[sm][sn] = __builtin_amdgcn_mfma_f32_16x16x32_bf16(af[sm], bfv[sn], acc[sm][sn], 0, 0, 0);
            __syncthreads();
        }
    }

    // epilogue: D[row = 4q + r][col = i16]; leaf = acc + cl[col]
    int segc[4]; float clv[4];
    #pragma unroll
    for (int sn = 0; sn < 4; ++sn) {
        const int col = blockN + wx * 64 + sn * 16 + i16;
        segc[sn] = seg[col];
        clv[sn]  = cl[col];
    }
    #pragma unroll
    for (int sm = 0; sm < 4; ++sm)
        #pragma unroll
        for (int sn = 0; sn < 4; ++sn)
            #pragma unroll
            for (int r = 0; r < 4; ++r) {
                const int rl = wy * 64 + sm * 16 + 4 * q + r;
                atomicMax(&pmax[rl * 16 + segc[sn]], f2ord(acc[sm][sn][r] + clv[sn]));
            }
    __syncthreads();
    #pragma unroll
    for (int j = 0; j < 8; ++j) {
        int idx = tid + j * 256;                       // 0..2047
        pp[((long)nTile << 19) + ((blockM + (idx >> 4)) << 4) + (idx & 15)] = pmax[idx];
    }
}

// ---------------- finalize: max over 8 partials + softmax ----------------
__global__ __launch_bounds__(256) void finalize(const u32* __restrict__ pp,
                                                float* __restrict__ out) {
    const int tid = threadIdx.x;
    const long row = (long)blockIdx.x * 16 + (tid >> 4);
    const int t = tid & 15;
    u32 m = 0;
    #pragma unroll
    for (int p = 0; p < 8; ++p)
        m = max(m, pp[((long)p << 19) + (row << 4) + t]);
    float logit = ord2f(m);
    float rm = logit;
    #pragma unroll
    for (int d = 8; d >= 1; d >>= 1) rm = fmaxf(rm, __shfl_xor(rm, d, 16));
    float e = __expf(logit - rm);
    float s = e;
    #pragma unroll
    for (int d = 8; d >= 1; d >>= 1) s += __shfl_xor(s, d, 16);
    out[(row << 4) + t] = e / s;
}

// ---------------- launch ----------------
extern "C" void kernel_launch(void* const* d_in, const int* in_sizes, int n_in,
                              void* d_out, int out_size, void* d_ws, size_t ws_size,
                              hipStream_t stream) {
    const float* x  = (const float*)d_in[0];
    const float* Wd = (const float*)d_in[1];
    const float* bd = (const float*)d_in[2];
    const float* Wa = (const float*)d_in[3];
    const float* ba = (const float*)d_in[4];
    const float* Wl = (const float*)d_in[5];
    const int*  seg = (const int*)d_in[6];
    float* out = (float*)d_out;

    char* ws = (char*)d_ws;
    u16*   xb   = (u16*)(ws);                      //   8,388,608 B  x bf16 [32768,128]
    u16*   w1b  = (u16*)(ws + 8388608);            //     262,144 B  W1 bf16 [1024,128]
    float* bb   = (float*)(ws + 8650752);          //       4,096 B  bias [1024]
    u16*   w1t  = (u16*)(ws + 8654848);            //     262,144 B  W1^T bf16 [128,1024]
    u16*   wsb  = (u16*)(ws + 8916992);            //   2,097,152 B  Ws bf16 [1024,1024]
    u16*   dlb  = (u16*)(ws + 11014144);           //   2,097,152 B  Dl bf16 [1024,1024]
    u16*   wcb  = (u16*)(ws + 13111296);           //     262,144 B  Wc bf16 [1024,128]
    float* clp  = (float*)(ws + 13373440);         //       4,096 B  cl fp32 [1024]
    u16*   habs = (u16*)(ws + 13377536);           //  67,108,864 B  |h| bf16 [32768,1024]
    u32*   pp   = (u32*)(ws + 80486400);           //  16,777,216 B  pooledPart u32 [8][32768][16]
    // total ws use: 97,263,616 B (~93 MiB)

    setup_all<<<3136, 256, 0, stream>>>(x, Wd, bd, Wa, ba, Wl,
                                        xb, w1b, bb, w1t, wsb, dlb, clp);
    gemm_wc  <<<8, 256, 0, stream>>>(dlb, w1t, wcb);
    gemm_h   <<<dim3(8, 256), 256, 0, stream>>>(xb, w1b, bb, habs);
    gemm_leaf<<<dim3(8, 256), 256, 0, stream>>>(habs, xb, wsb, wcb, clp, seg, pp);
    finalize <<<2048, 256, 0, stream>>>(pp, out);
}

// Round 9
// 240.445 us; speedup vs baseline: 1.3969x; 1.0117x over previous
//
#include <hip/hip_runtime.h>
#include <hip/hip_bf16.h>
#include <cstdint>
#include <cmath>

#define AS1 __attribute__((address_space(1)))
#define AS3 __attribute__((address_space(3)))

typedef unsigned short u16;
typedef uint32_t u32;
typedef __attribute__((ext_vector_type(8))) __bf16 bf16x8;
typedef __attribute__((ext_vector_type(8))) unsigned short u16x8;
typedef __attribute__((ext_vector_type(4))) float f32x4;

// fp32 -> bf16 round-to-nearest-even
__device__ __forceinline__ u16 f2bf(float f) {
    uint32_t u = __builtin_bit_cast(uint32_t, f);
    return (u16)((u + 0x7fffu + ((u >> 16) & 1u)) >> 16);
}

// order-preserving float -> u32 map (for integer atomicMax); 0 is below all reals
__device__ __forceinline__ u32 f2ord(float f) {
    u32 u = __builtin_bit_cast(u32, f);
    return u ^ (u32)(((int32_t)u >> 31) | 0x80000000);
}
__device__ __forceinline__ float ord2f(u32 v) {
    u32 u = (v & 0x80000000u) ? (v ^ 0x80000000u) : ~v;
    return __builtin_bit_cast(float, u);
}

// ---------------- fused setup ----------------
// ALGEBRA: relu(h)=(h+|h|)/2, relu(-h)=(|h|-h)/2  =>
//   leaf = |h| @ Ws^T + x @ Wc^T + cl,
//   Ws = (Wl[:, :1023] + Wl[:, 1023:])/2      [1024 x 1024 bf16, col 1023 = 0]
//   Dl = Wl[:, :1023] - Wl[:, 1023:]          [1024 x 1024 bf16, col 1023 = 0]
//   Wc = 0.5 * Dl @ W1  (via MFMA, fused into gemm_hwc)   [1024 x 128 bf16]
//   cl = 0.5 * Dl @ b1  (fp32, fused here)    [1024]
__global__ void setup_all(const float* __restrict__ x,
                          const float* __restrict__ Wd, const float* __restrict__ bd,
                          const float* __restrict__ Wa, const float* __restrict__ ba,
                          const float* __restrict__ Wl,
                          u16* __restrict__ xb, u16* __restrict__ w1b,
                          float* __restrict__ bb, u16* __restrict__ w1t,
                          u16* __restrict__ wsb, u16* __restrict__ dlb,
                          float* __restrict__ cl) {
    __shared__ float cred[256];
    const int b = blockIdx.x;
    const int tid = threadIdx.x;
    if (b < 2048) {
        long idx = (long)(b * 256 + tid) * 8;
        float4 a = *(const float4*)(x + idx);
        float4 c = *(const float4*)(x + idx + 4);
        u16x8 o;
        o[0]=f2bf(a.x); o[1]=f2bf(a.y); o[2]=f2bf(a.z); o[3]=f2bf(a.w);
        o[4]=f2bf(c.x); o[5]=f2bf(c.y); o[6]=f2bf(c.z); o[7]=f2bf(c.w);
        *(u16x8*)(xb + idx) = o;
    } else if (b < 2112) {
        int t = (b - 2048) * 256 + tid;   // 16384 threads
        int row = t >> 4, g = (t & 15) * 8;
        const float* src = nullptr;
        if (row < 511)       src = Wd + row * 128 + g;
        else if (row < 1023) src = Wa + (row - 511) * 128 + g;
        u16x8 o = 0;
        if (src) {
            #pragma unroll
            for (int j = 0; j < 8; ++j) o[j] = f2bf(src[j]);
        }
        *(u16x8*)(w1b + row * 128 + g) = o;
        #pragma unroll
        for (int j = 0; j < 8; ++j) w1t[(g + j) * 1024 + row] = o[j];
        if ((t & 15) == 0)
            bb[row] = row < 511 ? bd[row] : (row < 1023 ? ba[row - 511] : 0.f);
    } else if (b < 2624) {
        int t = (b - 2112) * 256 + tid;   // 131072 threads
        int row = t >> 7, g = (t & 127) * 8;
        const float* src = Wl + (long)row * 2046;
        u16x8 o;
        #pragma unroll
        for (int j = 0; j < 8; ++j) {
            int c = g + j;
            o[j] = (c < 1023) ? f2bf(0.5f * (src[c] + src[1023 + c])) : (u16)0;
        }
        *(u16x8*)(wsb + (long)row * 1024 + g) = o;
    } else {
        const int l0 = (b - 2624) * 2;
        const int lo = tid >> 7, g = (tid & 127) * 8;
        const float* src = Wl + (long)(l0 + lo) * 2046;
        u16x8 o;
        float part = 0.f;
        #pragma unroll
        for (int j = 0; j < 8; ++j) {
            int c = g + j;
            float v = (c < 1023) ? (src[c] - src[1023 + c]) : 0.f;
            o[j] = f2bf(v);
            float b1 = c < 511 ? bd[c] : (c < 1023 ? ba[c - 511] : 0.f);
            part += v * b1;
        }
        *(u16x8*)(dlb + (long)(l0 + lo) * 1024 + g) = o;
        cred[tid] = part;
        __syncthreads();
        if (tid < 2) {
            float s = 0.f;
            #pragma unroll
            for (int k = 0; k < 128; ++k) s += cred[tid * 128 + k];
            cl[l0 + tid] = 0.5f * s;
        }
    }
}

// ---------------- gemm_hwc: fused habs-GEMM + Wc-GEMM ----------------
// y < 256: habs = |xb @ w1b^T + bb|  [32768,1024]. SINGLE-STAGE K: all 4 BK=32 chunks
//   of A and B staged at once (64 KB LDS), ONE barrier drain instead of 4 (r8's 4-iter
//   loop was drain-dominated: ~70 us vs ~15 us write floor). XCD swizzle as before.
//   Epilogue: obuf overlay (union), 8x coalesced 16B stores/thread.
// y == 256: Wc = 0.5 * dlb @ w1t^T  [1024,128], 8 blocks (x = mTile), K=1024 looped.
__global__ __launch_bounds__(256) void gemm_hwc(
        const u16* __restrict__ xb, const u16* __restrict__ w1b,
        const float* __restrict__ bb,
        const u16* __restrict__ dlb, const u16* __restrict__ w1t,
        u16* __restrict__ habs, u16* __restrict__ wcb) {
    __shared__ union SharedU {
        struct { u16 As[4 * 4096]; u16 Bs[4 * 4096]; } s;  // 4 chunks x [128][32] each
        u16 obuf[128 * 136];                                // h epilogue overlay
    } sh;
    const int tid  = threadIdx.x;
    const int lane = tid & 63, wave = tid >> 6;
    const int wy = wave >> 1, wx = wave & 1;
    const int i16 = lane & 15, q = lane >> 4;
    const int cA = wave * 2, srow = lane >> 2, scol = (lane & 3) * 8;

    f32x4 acc[4][4];
    #pragma unroll
    for (int m = 0; m < 4; ++m)
        #pragma unroll
        for (int n = 0; n < 4; ++n) acc[m][n] = f32x4{0.f,0.f,0.f,0.f};

    if (blockIdx.y == 256) {
        // ---- wc role: K=1024 looped over chunk slot 0 ----
        const long blockM = (long)blockIdx.x * 128;
        const int koff = (blockIdx.x * 4) & 31;
        const u16* a0 = dlb + (blockM + cA * 16 + srow) * 1024 + scol;
        const u16* a1 = dlb + (blockM + (cA + 1) * 16 + srow) * 1024 + scol;
        const u16* b0 = w1t + (long)(cA * 16 + srow) * 1024 + scol;
        const u16* b1 = w1t + (long)((cA + 1) * 16 + srow) * 1024 + scol;
        for (int it = 0; it < 32; ++it) {
            const int k0 = ((it + koff) & 31) << 5;
            __builtin_amdgcn_global_load_lds((const AS1 void*)(a0 + k0), (AS3 void*)&sh.s.As[cA * 512],       16, 0, 0);
            __builtin_amdgcn_global_load_lds((const AS1 void*)(a1 + k0), (AS3 void*)&sh.s.As[(cA + 1) * 512], 16, 0, 0);
            __builtin_amdgcn_global_load_lds((const AS1 void*)(b0 + k0), (AS3 void*)&sh.s.Bs[cA * 512],       16, 0, 0);
            __builtin_amdgcn_global_load_lds((const AS1 void*)(b1 + k0), (AS3 void*)&sh.s.Bs[(cA + 1) * 512], 16, 0, 0);
            __syncthreads();
            bf16x8 af[4], bfv[4];
            #pragma unroll
            for (int s = 0; s < 4; ++s) {
                af[s]  = *(const bf16x8*)&sh.s.As[(wy * 64 + s * 16 + i16) * 32 + q * 8];
                bfv[s] = *(const bf16x8*)&sh.s.Bs[(wx * 64 + s * 16 + i16) * 32 + q * 8];
            }
            #pragma unroll
            for (int sm = 0; sm < 4; ++sm)
                #pragma unroll
                for (int sn = 0; sn < 4; ++sn)
                    acc[sm][sn] = __builtin_amdgcn_mfma_f32_16x16x32_bf16(af[sm], bfv[sn], acc[sm][sn], 0, 0, 0);
            __syncthreads();
        }
        #pragma unroll
        for (int sm = 0; sm < 4; ++sm)
            #pragma unroll
            for (int sn = 0; sn < 4; ++sn) {
                const int col = wx * 64 + sn * 16 + i16;     // 0..127
                #pragma unroll
                for (int r = 0; r < 4; ++r) {
                    const long row = blockM + wy * 64 + sm * 16 + 4 * q + r;
                    wcb[row * 128 + col] = f2bf(0.5f * acc[sm][sn][r]);
                }
            }
        return;
    }

    // ---- h role ----
    const int xcd = blockIdx.x, y = blockIdx.y;
    const long blockM = (long)(xcd * 32 + (y >> 3)) * 128;
    const int  blockN = (y & 7) * 128;

    const u16* a0 = xb + (blockM + cA * 16 + srow) * 128 + scol;
    const u16* a1 = xb + (blockM + (cA + 1) * 16 + srow) * 128 + scol;
    const u16* b0 = w1b + ((long)blockN + cA * 16 + srow) * 128 + scol;
    const u16* b1 = w1b + ((long)blockN + (cA + 1) * 16 + srow) * 128 + scol;
    #pragma unroll
    for (int kc = 0; kc < 4; ++kc) {
        const int k0 = kc * 32;
        __builtin_amdgcn_global_load_lds((const AS1 void*)(a0 + k0), (AS3 void*)&sh.s.As[kc * 4096 + cA * 512],       16, 0, 0);
        __builtin_amdgcn_global_load_lds((const AS1 void*)(a1 + k0), (AS3 void*)&sh.s.As[kc * 4096 + (cA + 1) * 512], 16, 0, 0);
        __builtin_amdgcn_global_load_lds((const AS1 void*)(b0 + k0), (AS3 void*)&sh.s.Bs[kc * 4096 + cA * 512],       16, 0, 0);
        __builtin_amdgcn_global_load_lds((const AS1 void*)(b1 + k0), (AS3 void*)&sh.s.Bs[kc * 4096 + (cA + 1) * 512], 16, 0, 0);
    }
    float bv[4];
    #pragma unroll
    for (int sn = 0; sn < 4; ++sn) bv[sn] = bb[blockN + wx * 64 + sn * 16 + i16];
    __syncthreads();

    #pragma unroll
    for (int ks = 0; ks < 4; ++ks) {
        bf16x8 af[4], bfv[4];
        #pragma unroll
        for (int s = 0; s < 4; ++s) {
            af[s]  = *(const bf16x8*)&sh.s.As[ks * 4096 + (wy * 64 + s * 16 + i16) * 32 + q * 8];
            bfv[s] = *(const bf16x8*)&sh.s.Bs[ks * 4096 + (wx * 64 + s * 16 + i16) * 32 + q * 8];
        }
        #pragma unroll
        for (int sm = 0; sm < 4; ++sm)
            #pragma unroll
            for (int sn = 0; sn < 4; ++sn)
                acc[sm][sn] = __builtin_amdgcn_mfma_f32_16x16x32_bf16(af[sm], bfv[sn], acc[sm][sn], 0, 0, 0);
    }
    __syncthreads();   // all LDS reads done before obuf overlays As/Bs

    #pragma unroll
    for (int sm = 0; sm < 4; ++sm)
        #pragma unroll
        for (int sn = 0; sn < 4; ++sn)
            #pragma unroll
            for (int r = 0; r < 4; ++r)
                sh.obuf[(wy * 64 + sm * 16 + 4 * q + r) * 136 + wx * 64 + sn * 16 + i16] =
                    f2bf(fabsf(acc[sm][sn][r] + bv[sn]));
    __syncthreads();
    const int cg = (tid & 15) * 8;
    #pragma unroll
    for (int it = 0; it < 8; ++it) {
        const int row = it * 16 + (tid >> 4);
        *(u16x8*)&habs[(blockM + row) * 1024 + blockN + cg] =
            *(const u16x8*)&sh.obuf[row * 136 + cg];
    }
}

// ---------------- GEMM2': leaf = habs@Ws^T + xb@Wc^T + cl, fused ragged-max ----------
// (CONTROL: unchanged from round 8)
__global__ __launch_bounds__(256) void gemm_leaf(const u16* __restrict__ habs,
        const u16* __restrict__ xb, const u16* __restrict__ wsb,
        const u16* __restrict__ wcb, const float* __restrict__ cl,
        const int* __restrict__ seg, u32* __restrict__ pp) {
    __shared__ u16 As[128 * 32];
    __shared__ u16 Bs[128 * 32];
    __shared__ u32 pmax[128 * 16];
    const int tid  = threadIdx.x;
    const int lane = tid & 63, wave = tid >> 6;
    const int wy = wave >> 1, wx = wave & 1;
    const int i16 = lane & 15, q = lane >> 4;
    const int xcd = blockIdx.x, y = blockIdx.y;
    const int nTile = y & 7;
    const long blockM = (long)(xcd * 32 + (y >> 3)) * 128;
    const int  blockN = nTile * 128;
    const int  koff = ((y >> 3) * 2) & 31;

    #pragma unroll
    for (int j = 0; j < 8; ++j) pmax[tid + j * 256] = 0u;   // below all reals

    f32x4 acc[4][4];
    #pragma unroll
    for (int m = 0; m < 4; ++m)
        #pragma unroll
        for (int n = 0; n < 4; ++n) acc[m][n] = f32x4{0.f,0.f,0.f,0.f};

    const int cA = wave * 2, srow = lane >> 2, scol = (lane & 3) * 8;
    // phase 1: habs (stride 1024) x wsb (stride 1024)
    {
        const u16* a0 = habs + (blockM + cA * 16 + srow) * 1024 + scol;
        const u16* a1 = habs + (blockM + (cA + 1) * 16 + srow) * 1024 + scol;
        const u16* b0 = wsb + ((long)blockN + cA * 16 + srow) * 1024 + scol;
        const u16* b1 = wsb + ((long)blockN + (cA + 1) * 16 + srow) * 1024 + scol;
        for (int it = 0; it < 32; ++it) {
            const int k0 = ((it + koff) & 31) << 5;
            __builtin_amdgcn_global_load_lds((const AS1 void*)(a0 + k0), (AS3 void*)&As[cA * 512],       16, 0, 0);
            __builtin_amdgcn_global_load_lds((const AS1 void*)(a1 + k0), (AS3 void*)&As[(cA + 1) * 512], 16, 0, 0);
            __builtin_amdgcn_global_load_lds((const AS1 void*)(b0 + k0), (AS3 void*)&Bs[cA * 512],       16, 0, 0);
            __builtin_amdgcn_global_load_lds((const AS1 void*)(b1 + k0), (AS3 void*)&Bs[(cA + 1) * 512], 16, 0, 0);
            __syncthreads();
            bf16x8 af[4], bfv[4];
            #pragma unroll
            for (int s = 0; s < 4; ++s) {
                af[s]  = *(const bf16x8*)&As[(wy * 64 + s * 16 + i16) * 32 + q * 8];
                bfv[s] = *(const bf16x8*)&Bs[(wx * 64 + s * 16 + i16) * 32 + q * 8];
            }
            #pragma unroll
            for (int sm = 0; sm < 4; ++sm)
                #pragma unroll
                for (int sn = 0; sn < 4; ++sn)
                    acc[sm][sn] = __builtin_amdgcn_mfma_f32_16x16x32_bf16(af[sm], bfv[sn], acc[sm][sn], 0, 0, 0);
            __syncthreads();
        }
    }
    // phase 2: xb (stride 128) x wcb (stride 128)
    {
        const u16* a0 = xb + (blockM + cA * 16 + srow) * 128 + scol;
        const u16* a1 = xb + (blockM + (cA + 1) * 16 + srow) * 128 + scol;
        const u16* b0 = wcb + ((long)blockN + cA * 16 + srow) * 128 + scol;
        const u16* b1 = wcb + ((long)blockN + (cA + 1) * 16 + srow) * 128 + scol;
        for (int it = 0; it < 4; ++it) {
            const int k0 = it << 5;
            __builtin_amdgcn_global_load_lds((const AS1 void*)(a0 + k0), (AS3 void*)&As[cA * 512],       16, 0, 0);
            __builtin_amdgcn_global_load_lds((const AS1 void*)(a1 + k0), (AS3 void*)&As[(cA + 1) * 512], 16, 0, 0);
            __builtin_amdgcn_global_load_lds((const AS1 void*)(b0 + k0), (AS3 void*)&Bs[cA * 512],       16, 0, 0);
            __builtin_amdgcn_global_load_lds((const AS1 void*)(b1 + k0), (AS3 void*)&Bs[(cA + 1) * 512], 16, 0, 0);
            __syncthreads();
            bf16x8 af[4], bfv[4];
            #pragma unroll
            for (int s = 0; s < 4; ++s) {
                af[s]  = *(const bf16x8*)&As[(wy * 64 + s * 16 + i16) * 32 + q * 8];
                bfv[s] = *(const bf16x8*)&Bs[(wx * 64 + s * 16 + i16) * 32 + q * 8];
            }
            #pragma unroll
            for (int sm = 0; sm < 4; ++sm)
                #pragma unroll
                for (int sn = 0; sn < 4; ++sn)
                    acc[sm][sn] = __builtin_amdgcn_mfma_f32_16x16x32_bf16(af[sm], bfv[sn], acc[sm][sn], 0, 0, 0);
            __syncthreads();
        }
    }

    // epilogue: D[row = 4q + r][col = i16]; leaf = acc + cl[col]
    int segc[4]; float clv[4];
    #pragma unroll
    for (int sn = 0; sn < 4; ++sn) {
        const int col = blockN + wx * 64 + sn * 16 + i16;
        segc[sn] = seg[col];
        clv[sn]  = cl[col];
    }
    #pragma unroll
    for (int sm = 0; sm < 4; ++sm)
        #pragma unroll
        for (int sn = 0; sn < 4; ++sn)
            #pragma unroll
            for (int r = 0; r < 4; ++r) {
                const int rl = wy * 64 + sm * 16 + 4 * q + r;
                atomicMax(&pmax[rl * 16 + segc[sn]], f2ord(acc[sm][sn][r] + clv[sn]));
            }
    __syncthreads();
    #pragma unroll
    for (int j = 0; j < 8; ++j) {
        int idx = tid + j * 256;                       // 0..2047
        pp[((long)nTile << 19) + ((blockM + (idx >> 4)) << 4) + (idx & 15)] = pmax[idx];
    }
}

// ---------------- finalize: max over 8 partials + softmax ----------------
__global__ __launch_bounds__(256) void finalize(const u32* __restrict__ pp,
                                                float* __restrict__ out) {
    const int tid = threadIdx.x;
    const long row = (long)blockIdx.x * 16 + (tid >> 4);
    const int t = tid & 15;
    u32 m = 0;
    #pragma unroll
    for (int p = 0; p < 8; ++p)
        m = max(m, pp[((long)p << 19) + (row << 4) + t]);
    float logit = ord2f(m);
    float rm = logit;
    #pragma unroll
    for (int d = 8; d >= 1; d >>= 1) rm = fmaxf(rm, __shfl_xor(rm, d, 16));
    float e = __expf(logit - rm);
    float s = e;
    #pragma unroll
    for (int d = 8; d >= 1; d >>= 1) s += __shfl_xor(s, d, 16);
    out[(row << 4) + t] = e / s;
}

// ---------------- launch ----------------
extern "C" void kernel_launch(void* const* d_in, const int* in_sizes, int n_in,
                              void* d_out, int out_size, void* d_ws, size_t ws_size,
                              hipStream_t stream) {
    const float* x  = (const float*)d_in[0];
    const float* Wd = (const float*)d_in[1];
    const float* bd = (const float*)d_in[2];
    const float* Wa = (const float*)d_in[3];
    const float* ba = (const float*)d_in[4];
    const float* Wl = (const float*)d_in[5];
    const int*  seg = (const int*)d_in[6];
    float* out = (float*)d_out;

    char* ws = (char*)d_ws;
    u16*   xb   = (u16*)(ws);                      //   8,388,608 B  x bf16 [32768,128]
    u16*   w1b  = (u16*)(ws + 8388608);            //     262,144 B  W1 bf16 [1024,128]
    float* bb   = (float*)(ws + 8650752);          //       4,096 B  bias [1024]
    u16*   w1t  = (u16*)(ws + 8654848);            //     262,144 B  W1^T bf16 [128,1024]
    u16*   wsb  = (u16*)(ws + 8916992);            //   2,097,152 B  Ws bf16 [1024,1024]
    u16*   dlb  = (u16*)(ws + 11014144);           //   2,097,152 B  Dl bf16 [1024,1024]
    u16*   wcb  = (u16*)(ws + 13111296);           //     262,144 B  Wc bf16 [1024,128]
    float* clp  = (float*)(ws + 13373440);         //       4,096 B  cl fp32 [1024]
    u16*   habs = (u16*)(ws + 13377536);           //  67,108,864 B  |h| bf16 [32768,1024]
    u32*   pp   = (u32*)(ws + 80486400);           //  16,777,216 B  pooledPart u32 [8][32768][16]
    // total ws use: 97,263,616 B (~93 MiB)

    setup_all<<<3136, 256, 0, stream>>>(x, Wd, bd, Wa, ba, Wl,
                                        xb, w1b, bb, w1t, wsb, dlb, clp);
    gemm_hwc <<<dim3(8, 257), 256, 0, stream>>>(xb, w1b, bb, dlb, w1t, habs, wcb);
    gemm_leaf<<<dim3(8, 256), 256, 0, stream>>>(habs, xb, wsb, wcb, clp, seg, pp);
    finalize <<<2048, 256, 0, stream>>>(pp, out);
}